// Round 4
// baseline (299.264 us; speedup 1.0000x reference)
//
#include <hip/hip_runtime.h>
#include <math.h>

#define H_N 1024
#define M_N 8
#define HM 8192

typedef float f32x4 __attribute__((ext_vector_type(4)));

static __device__ __forceinline__ float log_eps(float x) {
    const float EPS_TINY = 1.17549435e-38f;
    return __logf(x <= 0.0f ? EPS_TINY : x);
}

// ---------------- kernel 1: st_acc[j] += sum_i w[i][j] * o[i] (split-K partials) ----
__global__ __launch_bounds__(256) void gemv_partial(const float* __restrict__ w,
                                                    const float* __restrict__ o,
                                                    float* __restrict__ st_acc) {
    const int jb = blockIdx.x & 7;   // 8 j-blocks of 1024 columns
    const int ic = blockIdx.x >> 3;  // 64 i-chunks of 128 rows
    const int j0 = jb * 1024 + threadIdx.x * 4;
    const int i0 = ic * 128;
    float ax = 0.f, ay = 0.f, az = 0.f, aw = 0.f;
    const float* wp = w + (size_t)i0 * HM + j0;
#pragma unroll 4
    for (int i = 0; i < 128; ++i) {
        const float ov = o[i0 + i];
        const f32x4 wv = *reinterpret_cast<const f32x4*>(wp);
        ax += wv.x * ov; ay += wv.y * ov; az += wv.z * ov; aw += wv.w * ov;
        wp += HM;
    }
    atomicAdd(&st_acc[j0 + 0], ax);
    atomicAdd(&st_acc[j0 + 1], ay);
    atomicAdd(&st_acc[j0 + 2], az);
    atomicAdd(&st_acc[j0 + 3], aw);
}

// ---------------- kernel 2: per-row state update + softmax + small outputs ---------
__global__ __launch_bounds__(256) void row_kernel(
    const float* __restrict__ x, const float* __restrict__ s,
    const float* __restrict__ a, const float* __restrict__ zi,
    const float* __restrict__ zj, const float* __restrict__ p,
    const float* __restrict__ pi, const float* __restrict__ pj,
    const float* __restrict__ b, const float* __restrict__ noise,
    const float* __restrict__ ga, const float* __restrict__ gw,
    const float* __restrict__ gb, const float* __restrict__ gs,
    const float* __restrict__ k, const float* __restrict__ st_acc,
    float* __restrict__ out) {
    const int r = blockIdx.x * blockDim.x + threadIdx.x;
    if (r >= H_N) return;

    const float gwv = gw[0], gav = ga[0], gbv = gb[0], gsv = gs[0], kv = k[0], pv = p[0];
    const float c = kv * 1e-4f;   // k*DT/TP

    float* o_new  = out;
    float* s_new  = out + (size_t)HM;
    float* a_new  = out + (size_t)2 * HM;
    float* zi_new = out + (size_t)3 * HM;
    float* zj_new = out + (size_t)4 * HM;
    float* p_new  = out + (size_t)5 * HM;          // 1 element
    float* pi_new = out + (size_t)5 * HM + 1;
    float* pj_new = out + (size_t)6 * HM + 1;
    float* b_new  = out + (size_t)7 * HM + 1 + (size_t)2 * HM * HM;

    const int base = r * M_N;
    float sv[M_N], ev[M_N];
    float mx = -3.0e38f;
#pragma unroll
    for (int m = 0; m < M_N; ++m) {
        const int i = base + m;
        const float st = gwv * (b[i] + st_acc[i]);
        const float sn = s[i] + 0.02f * (st - a[i] + log_eps(x[i]) + gsv * noise[i] - s[i]);
        sv[m] = sn;
        mx = fmaxf(mx, sn);
    }
    float sum = 0.f;
#pragma unroll
    for (int m = 0; m < M_N; ++m) { ev[m] = __expf(sv[m] - mx); sum += ev[m]; }
    const float rs = 1.0f / sum;
#pragma unroll
    for (int m = 0; m < M_N; ++m) {
        const int i = base + m;
        const float on  = ev[m] * rs;
        const float an  = a[i]  + (float)(0.001 / 2.7)  * (gav * on - a[i]);
        const float zin = zi[i] + (float)(0.001 / 0.24) * (on - zi[i]);
        const float zjn = zj[i] + (float)(0.001 / 0.24) * (on - zj[i]);
        const float pin = pi[i] + c * (zin - pi[i]);
        const float pjn = pj[i] + c * (zjn - pj[i]);
        o_new[i]  = on;
        s_new[i]  = sv[m];
        a_new[i]  = an;
        zi_new[i] = zin;
        zj_new[i] = zjn;
        pi_new[i] = pin;
        pj_new[i] = pjn;
        b_new[i]  = gbv * log_eps(pjn);
    }
    if (r == 0) p_new[0] = pv + c * (1.0f - pv);
}

// ---------------- kernel 3: pij_new + w_new (dominant, ~768 MB traffic) ------------
// Thread t owns OUTPUT elements [4t+3, 4t+7): stores to out+57345+e0 are 16B-aligned
// -> two aligned nontemporal dwordx4 stores. Input: each lane loads its own aligned
// quad pij4[t] and gets the 3 straddling elements from lane+1 via __shfl_down (the
// last active lane of each wave does one extra direct load instead).
__global__ __launch_bounds__(256) void outer_kernel(
    const float* __restrict__ pij, const float* __restrict__ out_ro,
    float* __restrict__ out, const float* __restrict__ p,
    const float* __restrict__ k) {
    const float* zi_new = out_ro + (size_t)3 * HM;
    const float* zj_new = out_ro + (size_t)4 * HM;
    const float* pi_new = out_ro + (size_t)5 * HM + 1;
    const float* pj_new = out_ro + (size_t)6 * HM + 1;
    float* pij_new = out + (size_t)7 * HM + 1;
    float* w_new   = pij_new + (size_t)HM * HM;

    const float kv = k[0], pv = p[0];
    const float c  = kv * 1e-4f;
    const float pn = pv + c * (1.0f - pv);

    const size_t N  = (size_t)HM * HM;
    const size_t NQ = (N - 4) / 4;          // 16777215 output quads starting at e=3
    const size_t stride = (size_t)gridDim.x * blockDim.x;
    size_t t = (size_t)blockIdx.x * blockDim.x + threadIdx.x;
    const int lane = threadIdx.x & 63;

    if (t == 0) {
        // head elements 0,1,2 (row 0) and tail element N-1 (row 8191, col 8191)
        const float zi0 = zi_new[0], pi0 = pi_new[0];
#pragma unroll
        for (int e = 0; e < 3; ++e) {
            const float pe = pij[e];
            const float q  = pe + c * (zi0 * zj_new[e] - pe);
            pij_new[e] = q;
            w_new[e]   = log_eps(__fdividef(pn * q, pi0 * pj_new[e]));
        }
        const size_t eN = N - 1;
        const float pe = pij[eN];
        const float q  = pe + c * (zi_new[HM - 1] * zj_new[HM - 1] - pe);
        pij_new[eN] = q;
        w_new[eN]   = log_eps(__fdividef(pn * q, pi_new[HM - 1] * pj_new[HM - 1]));
    }

    const f32x4* pij4 = reinterpret_cast<const f32x4*>(pij);
    for (; t < NQ; t += stride) {
        const f32x4 A = pij4[t];             // elements 4t .. 4t+3 (aligned, coalesced)
        const float p0 = A.w;
        float p1 = __shfl_down(A.x, 1);      // neighbor's elements 4t+4..4t+6
        float p2 = __shfl_down(A.y, 1);
        float p3 = __shfl_down(A.z, 1);
        if (lane == 63 || t == NQ - 1) {     // neighbor lane absent/inactive
            const f32x4 B = pij4[t + 1];     // t+1 <= N/4-1, always in range
            p1 = B.x; p2 = B.y; p3 = B.z;
        }

        const size_t e0 = 4 * t + 3;
        float q0, q1, q2, q3, w0, w1, w2, w3;
        const int J0 = (int)(e0 & (HM - 1));
        if (J0 != HM - 1) {                  // all four elements in one row (common)
            const int I = (int)(e0 >> 13);
            const float ziI = zi_new[I];
            const float piI = pi_new[I];
            const float zj0 = zj_new[J0], zj1 = zj_new[J0 + 1], zj2 = zj_new[J0 + 2], zj3 = zj_new[J0 + 3];
            const float pj0 = pj_new[J0], pj1 = pj_new[J0 + 1], pj2 = pj_new[J0 + 2], pj3 = pj_new[J0 + 3];
            q0 = p0 + c * (ziI * zj0 - p0);
            q1 = p1 + c * (ziI * zj1 - p1);
            q2 = p2 + c * (ziI * zj2 - p2);
            q3 = p3 + c * (ziI * zj3 - p3);
            w0 = log_eps(__fdividef(pn * q0, piI * pj0));
            w1 = log_eps(__fdividef(pn * q1, piI * pj1));
            w2 = log_eps(__fdividef(pn * q2, piI * pj2));
            w3 = log_eps(__fdividef(pn * q3, piI * pj3));
        } else {                             // straddles a row boundary (1/2048 quads)
            float pv4[4] = {p0, p1, p2, p3};
            float qq[4], ww[4];
#pragma unroll
            for (int m = 0; m < 4; ++m) {
                const size_t e = e0 + m;
                const int Im = (int)(e >> 13);
                const int Jm = (int)(e & (HM - 1));
                const float q = pv4[m] + c * (zi_new[Im] * zj_new[Jm] - pv4[m]);
                qq[m] = q;
                ww[m] = log_eps(__fdividef(pn * q, pi_new[Im] * pj_new[Jm]));
            }
            q0 = qq[0]; q1 = qq[1]; q2 = qq[2]; q3 = qq[3];
            w0 = ww[0]; w1 = ww[1]; w2 = ww[2]; w3 = ww[3];
        }

        f32x4 Q; Q.x = q0; Q.y = q1; Q.z = q2; Q.w = q3;
        f32x4 W; W.x = w0; W.y = w1; W.z = w2; W.w = w3;
        __builtin_nontemporal_store(Q, reinterpret_cast<f32x4*>(&pij_new[e0]));
        __builtin_nontemporal_store(W, reinterpret_cast<f32x4*>(&w_new[e0]));
    }
}

extern "C" void kernel_launch(void* const* d_in, const int* in_sizes, int n_in,
                              void* d_out, int out_size, void* d_ws, size_t ws_size,
                              hipStream_t stream) {
    const float* x     = (const float*)d_in[0];
    const float* s     = (const float*)d_in[1];
    const float* o     = (const float*)d_in[2];
    const float* a     = (const float*)d_in[3];
    const float* zi    = (const float*)d_in[4];
    const float* zj    = (const float*)d_in[5];
    const float* p     = (const float*)d_in[6];
    const float* pi    = (const float*)d_in[7];
    const float* pj    = (const float*)d_in[8];
    const float* pij   = (const float*)d_in[9];
    const float* b     = (const float*)d_in[10];
    const float* w     = (const float*)d_in[11];
    const float* noise = (const float*)d_in[12];
    const float* ga    = (const float*)d_in[13];
    const float* gw    = (const float*)d_in[14];
    const float* gb    = (const float*)d_in[15];
    const float* gs    = (const float*)d_in[16];
    const float* k     = (const float*)d_in[17];

    float* out = (float*)d_out;
    float* st_acc = (float*)d_ws;

    (void)hipMemsetAsync(st_acc, 0, HM * sizeof(float), stream);
    gemv_partial<<<512, 256, 0, stream>>>(w, o, st_acc);
    row_kernel<<<(H_N + 255) / 256, 256, 0, stream>>>(
        x, s, a, zi, zj, p, pi, pj, b, noise, ga, gw, gb, gs, k, st_acc, out);
    outer_kernel<<<2048, 256, 0, stream>>>(pij, out, out, p, k);
}

// Round 5
// 291.120 us; speedup vs baseline: 1.0280x; 1.0280x over previous
//
#include <hip/hip_runtime.h>
#include <math.h>

#define H_N 1024
#define M_N 8
#define HM 8192

typedef float f32x4 __attribute__((ext_vector_type(4)));

static __device__ __forceinline__ float log_eps(float x) {
    const float EPS_TINY = 1.17549435e-38f;
    return __logf(x <= 0.0f ? EPS_TINY : x);
}

// ---------------- kernel 1: st_acc[j] += sum_i w[i][j] * o[i] (split-K partials) ----
__global__ __launch_bounds__(256) void gemv_partial(const float* __restrict__ w,
                                                    const float* __restrict__ o,
                                                    float* __restrict__ st_acc) {
    const int jb = blockIdx.x & 7;   // 8 j-blocks of 1024 columns
    const int ic = blockIdx.x >> 3;  // 64 i-chunks of 128 rows
    const int j0 = jb * 1024 + threadIdx.x * 4;
    const int i0 = ic * 128;
    float ax = 0.f, ay = 0.f, az = 0.f, aw = 0.f;
    const float* wp = w + (size_t)i0 * HM + j0;
#pragma unroll 4
    for (int i = 0; i < 128; ++i) {
        const float ov = o[i0 + i];
        const f32x4 wv = *reinterpret_cast<const f32x4*>(wp);
        ax += wv.x * ov; ay += wv.y * ov; az += wv.z * ov; aw += wv.w * ov;
        wp += HM;
    }
    atomicAdd(&st_acc[j0 + 0], ax);
    atomicAdd(&st_acc[j0 + 1], ay);
    atomicAdd(&st_acc[j0 + 2], az);
    atomicAdd(&st_acc[j0 + 3], aw);
}

// ---------------- kernel 2: per-row state update + softmax + small outputs ---------
// Also writes +3-shifted aligned copies zjs/pjs into d_ws for outer_kernel's
// aligned dwordx4 loads: zjs[i-3] = zj_new[i], pjs[i-3] = pj_new[i].
__global__ __launch_bounds__(256) void row_kernel(
    const float* __restrict__ x, const float* __restrict__ s,
    const float* __restrict__ a, const float* __restrict__ zi,
    const float* __restrict__ zj, const float* __restrict__ p,
    const float* __restrict__ pi, const float* __restrict__ pj,
    const float* __restrict__ b, const float* __restrict__ noise,
    const float* __restrict__ ga, const float* __restrict__ gw,
    const float* __restrict__ gb, const float* __restrict__ gs,
    const float* __restrict__ k, const float* __restrict__ st_acc,
    float* __restrict__ zjs, float* __restrict__ pjs,
    float* __restrict__ out) {
    const int r = blockIdx.x * blockDim.x + threadIdx.x;
    if (r >= H_N) return;

    const float gwv = gw[0], gav = ga[0], gbv = gb[0], gsv = gs[0], kv = k[0], pv = p[0];
    const float c = kv * 1e-4f;   // k*DT/TP

    float* o_new  = out;
    float* s_new  = out + (size_t)HM;
    float* a_new  = out + (size_t)2 * HM;
    float* zi_new = out + (size_t)3 * HM;
    float* zj_new = out + (size_t)4 * HM;
    float* p_new  = out + (size_t)5 * HM;          // 1 element
    float* pi_new = out + (size_t)5 * HM + 1;
    float* pj_new = out + (size_t)6 * HM + 1;
    float* b_new  = out + (size_t)7 * HM + 1 + (size_t)2 * HM * HM;

    const int base = r * M_N;
    float sv[M_N], ev[M_N];
    float mx = -3.0e38f;
#pragma unroll
    for (int m = 0; m < M_N; ++m) {
        const int i = base + m;
        const float st = gwv * (b[i] + st_acc[i]);
        const float sn = s[i] + 0.02f * (st - a[i] + log_eps(x[i]) + gsv * noise[i] - s[i]);
        sv[m] = sn;
        mx = fmaxf(mx, sn);
    }
    float sum = 0.f;
#pragma unroll
    for (int m = 0; m < M_N; ++m) { ev[m] = __expf(sv[m] - mx); sum += ev[m]; }
    const float rs = 1.0f / sum;
#pragma unroll
    for (int m = 0; m < M_N; ++m) {
        const int i = base + m;
        const float on  = ev[m] * rs;
        const float an  = a[i]  + (float)(0.001 / 2.7)  * (gav * on - a[i]);
        const float zin = zi[i] + (float)(0.001 / 0.24) * (on - zi[i]);
        const float zjn = zj[i] + (float)(0.001 / 0.24) * (on - zj[i]);
        const float pin = pi[i] + c * (zin - pi[i]);
        const float pjn = pj[i] + c * (zjn - pj[i]);
        o_new[i]  = on;
        s_new[i]  = sv[m];
        a_new[i]  = an;
        zi_new[i] = zin;
        zj_new[i] = zjn;
        pi_new[i] = pin;
        pj_new[i] = pjn;
        b_new[i]  = gbv * log_eps(pjn);
        if (i >= 3) {                       // shifted aligned copies for outer_kernel
            zjs[i - 3] = zjn;
            pjs[i - 3] = pjn;
        }
    }
    if (r == 0) p_new[0] = pv + c * (1.0f - pv);
}

// ---------------- kernel 3: pij_new + w_new (dominant, ~768 MB traffic) ------------
// Thread t owns OUTPUT elements [4t+3, 4t+7): stores to out+57345+e0 are 16B-aligned.
// pij input: own aligned quad + 3 elements from lane+1 via __shfl_down.
// zj/pj: aligned dwordx4 from the +3-shifted ws copies. Plain stores (no NT).
__global__ __launch_bounds__(256) void outer_kernel(
    const float* __restrict__ pij, const float* __restrict__ out_ro,
    const float* __restrict__ zjs, const float* __restrict__ pjs,
    float* __restrict__ out, const float* __restrict__ p,
    const float* __restrict__ k) {
    const float* zi_new = out_ro + (size_t)3 * HM;
    const float* zj_new = out_ro + (size_t)4 * HM;
    const float* pi_new = out_ro + (size_t)5 * HM + 1;
    const float* pj_new = out_ro + (size_t)6 * HM + 1;
    float* pij_new = out + (size_t)7 * HM + 1;
    float* w_new   = pij_new + (size_t)HM * HM;

    const float kv = k[0], pv = p[0];
    const float c  = kv * 1e-4f;
    const float pn = pv + c * (1.0f - pv);

    const size_t N  = (size_t)HM * HM;
    const size_t NQ = (N - 4) / 4;          // 16777215 output quads starting at e=3
    const size_t stride = (size_t)gridDim.x * blockDim.x;
    size_t t = (size_t)blockIdx.x * blockDim.x + threadIdx.x;
    const int lane = threadIdx.x & 63;

    if (t == 0) {
        // head elements 0,1,2 (row 0) and tail element N-1 (row 8191, col 8191)
        const float zi0 = zi_new[0], pi0 = pi_new[0];
#pragma unroll
        for (int e = 0; e < 3; ++e) {
            const float pe = pij[e];
            const float q  = pe + c * (zi0 * zj_new[e] - pe);
            pij_new[e] = q;
            w_new[e]   = log_eps(__fdividef(pn * q, pi0 * pj_new[e]));
        }
        const size_t eN = N - 1;
        const float pe = pij[eN];
        const float q  = pe + c * (zi_new[HM - 1] * zj_new[HM - 1] - pe);
        pij_new[eN] = q;
        w_new[eN]   = log_eps(__fdividef(pn * q, pi_new[HM - 1] * pj_new[HM - 1]));
    }

    const f32x4* pij4 = reinterpret_cast<const f32x4*>(pij);
    for (; t < NQ; t += stride) {
        const f32x4 A = pij4[t];             // elements 4t .. 4t+3 (aligned, coalesced)
        const float p0 = A.w;
        float p1 = __shfl_down(A.x, 1);      // neighbor's elements 4t+4..4t+6
        float p2 = __shfl_down(A.y, 1);
        float p3 = __shfl_down(A.z, 1);
        if (lane == 63 || t == NQ - 1) {     // neighbor lane absent/inactive
            const f32x4 B = pij4[t + 1];     // t+1 <= N/4-1, always in range
            p1 = B.x; p2 = B.y; p3 = B.z;
        }

        const size_t e0 = 4 * t + 3;
        float q0, q1, q2, q3, w0, w1, w2, w3;
        const int J0 = (int)(e0 & (HM - 1));
        if (J0 != HM - 1) {                  // all four elements in one row (common)
            const int I = (int)(e0 >> 13);
            const float ziI = zi_new[I];
            const float piI = pi_new[I];
            const f32x4 zj4 = *reinterpret_cast<const f32x4*>(&zjs[J0 - 3]);  // aligned
            const f32x4 pj4 = *reinterpret_cast<const f32x4*>(&pjs[J0 - 3]);  // aligned
            q0 = p0 + c * (ziI * zj4.x - p0);
            q1 = p1 + c * (ziI * zj4.y - p1);
            q2 = p2 + c * (ziI * zj4.z - p2);
            q3 = p3 + c * (ziI * zj4.w - p3);
            w0 = log_eps(__fdividef(pn * q0, piI * pj4.x));
            w1 = log_eps(__fdividef(pn * q1, piI * pj4.y));
            w2 = log_eps(__fdividef(pn * q2, piI * pj4.z));
            w3 = log_eps(__fdividef(pn * q3, piI * pj4.w));
        } else {                             // straddles a row boundary (1/2048 quads)
            float pv4[4] = {p0, p1, p2, p3};
            float qq[4], ww[4];
#pragma unroll
            for (int m = 0; m < 4; ++m) {
                const size_t e = e0 + m;
                const int Im = (int)(e >> 13);
                const int Jm = (int)(e & (HM - 1));
                const float q = pv4[m] + c * (zi_new[Im] * zj_new[Jm] - pv4[m]);
                qq[m] = q;
                ww[m] = log_eps(__fdividef(pn * q, pi_new[Im] * pj_new[Jm]));
            }
            q0 = qq[0]; q1 = qq[1]; q2 = qq[2]; q3 = qq[3];
            w0 = ww[0]; w1 = ww[1]; w2 = ww[2]; w3 = ww[3];
        }

        f32x4 Q; Q.x = q0; Q.y = q1; Q.z = q2; Q.w = q3;
        f32x4 W; W.x = w0; W.y = w1; W.z = w2; W.w = w3;
        *reinterpret_cast<f32x4*>(&pij_new[e0]) = Q;   // aligned, plain (no NT)
        *reinterpret_cast<f32x4*>(&w_new[e0])   = W;   // aligned, plain (no NT)
    }
}

extern "C" void kernel_launch(void* const* d_in, const int* in_sizes, int n_in,
                              void* d_out, int out_size, void* d_ws, size_t ws_size,
                              hipStream_t stream) {
    const float* x     = (const float*)d_in[0];
    const float* s     = (const float*)d_in[1];
    const float* o     = (const float*)d_in[2];
    const float* a     = (const float*)d_in[3];
    const float* zi    = (const float*)d_in[4];
    const float* zj    = (const float*)d_in[5];
    const float* p     = (const float*)d_in[6];
    const float* pi    = (const float*)d_in[7];
    const float* pj    = (const float*)d_in[8];
    const float* pij   = (const float*)d_in[9];
    const float* b     = (const float*)d_in[10];
    const float* w     = (const float*)d_in[11];
    const float* noise = (const float*)d_in[12];
    const float* ga    = (const float*)d_in[13];
    const float* gw    = (const float*)d_in[14];
    const float* gb    = (const float*)d_in[15];
    const float* gs    = (const float*)d_in[16];
    const float* k     = (const float*)d_in[17];

    float* out    = (float*)d_out;
    float* st_acc = (float*)d_ws;
    float* zjs    = st_acc + HM;        // 8192 floats, 16B-aligned base
    float* pjs    = zjs + HM;           // 8192 floats, 16B-aligned base

    (void)hipMemsetAsync(st_acc, 0, HM * sizeof(float), stream);
    gemv_partial<<<512, 256, 0, stream>>>(w, o, st_acc);
    row_kernel<<<(H_N + 255) / 256, 256, 0, stream>>>(
        x, s, a, zi, zj, p, pi, pj, b, noise, ga, gw, gb, gs, k, st_acc, zjs, pjs, out);
    outer_kernel<<<2048, 256, 0, stream>>>(pij, out, zjs, pjs, out, p, k);
}

// Round 6
// 262.109 us; speedup vs baseline: 1.1418x; 1.1107x over previous
//
#include <hip/hip_runtime.h>
#include <math.h>

#define H_N 1024
#define M_N 8
#define HM 8192
#define NIC 64   // i-chunks for split-K gemv

typedef float f32x4 __attribute__((ext_vector_type(4)));

static __device__ __forceinline__ float log_eps(float x) {
    const float EPS_TINY = 1.17549435e-38f;
    return __logf(x <= 0.0f ? EPS_TINY : x);
}

// ---------------- kernel 1: pbuf[ic][j] = sum_{i in chunk ic} w[i][j] * o[i] -------
// No atomics: each (ic, j) partial is written exactly once, coalesced dwordx4.
__global__ __launch_bounds__(256) void gemv_partial(const float* __restrict__ w,
                                                    const float* __restrict__ o,
                                                    float* __restrict__ pbuf) {
    const int jb = blockIdx.x & 7;   // 8 j-blocks of 1024 columns
    const int ic = blockIdx.x >> 3;  // 64 i-chunks of 128 rows
    const int j0 = jb * 1024 + threadIdx.x * 4;
    const int i0 = ic * 128;
    f32x4 acc = {0.f, 0.f, 0.f, 0.f};
    const float* wp = w + (size_t)i0 * HM + j0;
#pragma unroll 4
    for (int i = 0; i < 128; ++i) {
        const float ov = o[i0 + i];
        const f32x4 wv = *reinterpret_cast<const f32x4*>(wp);
        acc.x += wv.x * ov; acc.y += wv.y * ov; acc.z += wv.z * ov; acc.w += wv.w * ov;
        wp += HM;
    }
    *reinterpret_cast<f32x4*>(&pbuf[(size_t)ic * HM + j0]) = acc;
}

// ---------------- kernel 2: reduce partials + per-row state update + softmax -------
__global__ __launch_bounds__(256) void row_kernel(
    const float* __restrict__ x, const float* __restrict__ s,
    const float* __restrict__ a, const float* __restrict__ zi,
    const float* __restrict__ zj, const float* __restrict__ p,
    const float* __restrict__ pi, const float* __restrict__ pj,
    const float* __restrict__ b, const float* __restrict__ noise,
    const float* __restrict__ ga, const float* __restrict__ gw,
    const float* __restrict__ gb, const float* __restrict__ gs,
    const float* __restrict__ k, const float* __restrict__ pbuf,
    float* __restrict__ out) {
    const int r = blockIdx.x * blockDim.x + threadIdx.x;
    if (r >= H_N) return;

    const float gwv = gw[0], gav = ga[0], gbv = gb[0], gsv = gs[0], kv = k[0], pv = p[0];
    const float c = kv * 1e-4f;   // k*DT/TP

    float* o_new  = out;
    float* s_new  = out + (size_t)HM;
    float* a_new  = out + (size_t)2 * HM;
    float* zi_new = out + (size_t)3 * HM;
    float* zj_new = out + (size_t)4 * HM;
    float* p_new  = out + (size_t)5 * HM;          // 1 element
    float* pi_new = out + (size_t)5 * HM + 1;
    float* pj_new = out + (size_t)6 * HM + 1;
    float* b_new  = out + (size_t)7 * HM + 1 + (size_t)2 * HM * HM;

    const int base = r * M_N;

    // reduce the 64 split-K partials for this row's 8 columns
    f32x4 r0 = {0.f, 0.f, 0.f, 0.f}, r1 = {0.f, 0.f, 0.f, 0.f};
#pragma unroll 8
    for (int ic = 0; ic < NIC; ++ic) {
        const float* pp = pbuf + (size_t)ic * HM + base;
        const f32x4 v0 = *reinterpret_cast<const f32x4*>(pp);
        const f32x4 v1 = *reinterpret_cast<const f32x4*>(pp + 4);
        r0.x += v0.x; r0.y += v0.y; r0.z += v0.z; r0.w += v0.w;
        r1.x += v1.x; r1.y += v1.y; r1.z += v1.z; r1.w += v1.w;
    }
    const float stv[M_N] = {r0.x, r0.y, r0.z, r0.w, r1.x, r1.y, r1.z, r1.w};

    float sv[M_N], ev[M_N];
    float mx = -3.0e38f;
#pragma unroll
    for (int m = 0; m < M_N; ++m) {
        const int i = base + m;
        const float st = gwv * (b[i] + stv[m]);
        const float sn = s[i] + 0.02f * (st - a[i] + log_eps(x[i]) + gsv * noise[i] - s[i]);
        sv[m] = sn;
        mx = fmaxf(mx, sn);
    }
    float sum = 0.f;
#pragma unroll
    for (int m = 0; m < M_N; ++m) { ev[m] = __expf(sv[m] - mx); sum += ev[m]; }
    const float rs = 1.0f / sum;
#pragma unroll
    for (int m = 0; m < M_N; ++m) {
        const int i = base + m;
        const float on  = ev[m] * rs;
        const float an  = a[i]  + (float)(0.001 / 2.7)  * (gav * on - a[i]);
        const float zin = zi[i] + (float)(0.001 / 0.24) * (on - zi[i]);
        const float zjn = zj[i] + (float)(0.001 / 0.24) * (on - zj[i]);
        const float pin = pi[i] + c * (zin - pi[i]);
        const float pjn = pj[i] + c * (zjn - pj[i]);
        o_new[i]  = on;
        s_new[i]  = sv[m];
        a_new[i]  = an;
        zi_new[i] = zin;
        zj_new[i] = zjn;
        pi_new[i] = pin;
        pj_new[i] = pjn;
        b_new[i]  = gbv * log_eps(pjn);
    }
    if (r == 0) p_new[0] = pv + c * (1.0f - pv);
}

// ---------------- kernel 3: pij_new + w_new (exact R1 version, 268.5 µs config) ----
__global__ __launch_bounds__(256) void outer_kernel(
    const float* __restrict__ pij, const float* __restrict__ out_ro,
    float* __restrict__ out, const float* __restrict__ p,
    const float* __restrict__ k) {
    const float* zi_new = out_ro + (size_t)3 * HM;
    const float* zj_new = out_ro + (size_t)4 * HM;
    const float* pi_new = out_ro + (size_t)5 * HM + 1;
    const float* pj_new = out_ro + (size_t)6 * HM + 1;
    float* pij_new = out + (size_t)7 * HM + 1;
    float* w_new   = pij_new + (size_t)HM * HM;

    const float kv = k[0], pv = p[0];
    const float c  = kv * 1e-4f;
    const float pn = pv + c * (1.0f - pv);

    const size_t nvec   = (size_t)HM * HM / 4;
    const size_t stride = (size_t)gridDim.x * blockDim.x;
    for (size_t v = (size_t)blockIdx.x * blockDim.x + threadIdx.x; v < nvec; v += stride) {
        const size_t idx = v * 4;
        const int I = (int)(idx >> 13);
        const int J = (int)(idx & 8191);
        const float ziI = zi_new[I];
        const float piI = pi_new[I];
        const f32x4 pv4 = *reinterpret_cast<const f32x4*>(&pij[idx]);
        const float zj0 = zj_new[J + 0], zj1 = zj_new[J + 1], zj2 = zj_new[J + 2], zj3 = zj_new[J + 3];
        const float pj0 = pj_new[J + 0], pj1 = pj_new[J + 1], pj2 = pj_new[J + 2], pj3 = pj_new[J + 3];

        const float q0 = pv4.x + c * (ziI * zj0 - pv4.x);
        const float q1 = pv4.y + c * (ziI * zj1 - pv4.y);
        const float q2 = pv4.z + c * (ziI * zj2 - pv4.z);
        const float q3 = pv4.w + c * (ziI * zj3 - pv4.w);

        pij_new[idx + 0] = q0;
        pij_new[idx + 1] = q1;
        pij_new[idx + 2] = q2;
        pij_new[idx + 3] = q3;

        const float v0 = __fdividef(pn * q0, piI * pj0);
        const float v1 = __fdividef(pn * q1, piI * pj1);
        const float v2 = __fdividef(pn * q2, piI * pj2);
        const float v3 = __fdividef(pn * q3, piI * pj3);

        w_new[idx + 0] = log_eps(v0);
        w_new[idx + 1] = log_eps(v1);
        w_new[idx + 2] = log_eps(v2);
        w_new[idx + 3] = log_eps(v3);
    }
}

extern "C" void kernel_launch(void* const* d_in, const int* in_sizes, int n_in,
                              void* d_out, int out_size, void* d_ws, size_t ws_size,
                              hipStream_t stream) {
    const float* x     = (const float*)d_in[0];
    const float* s     = (const float*)d_in[1];
    const float* o     = (const float*)d_in[2];
    const float* a     = (const float*)d_in[3];
    const float* zi    = (const float*)d_in[4];
    const float* zj    = (const float*)d_in[5];
    const float* p     = (const float*)d_in[6];
    const float* pi    = (const float*)d_in[7];
    const float* pj    = (const float*)d_in[8];
    const float* pij   = (const float*)d_in[9];
    const float* b     = (const float*)d_in[10];
    const float* w     = (const float*)d_in[11];
    const float* noise = (const float*)d_in[12];
    const float* ga    = (const float*)d_in[13];
    const float* gw    = (const float*)d_in[14];
    const float* gb    = (const float*)d_in[15];
    const float* gs    = (const float*)d_in[16];
    const float* k     = (const float*)d_in[17];

    float* out  = (float*)d_out;
    float* pbuf = (float*)d_ws;          // NIC * HM floats = 2 MB of scratch

    gemv_partial<<<512, 256, 0, stream>>>(w, o, pbuf);
    row_kernel<<<(H_N + 255) / 256, 256, 0, stream>>>(
        x, s, a, zi, zj, p, pi, pj, b, noise, ga, gw, gb, gs, k, pbuf, out);
    outer_kernel<<<2048, 256, 0, stream>>>(pij, out, out, p, k);
}